// Round 1
// baseline (678.003 us; speedup 1.0000x reference)
//
#include <hip/hip_runtime.h>
#include <stdint.h>

// Problem: BitLinear forward.
//   x: [8192, 4096] fp32, weight: [4096, 4096] fp32 ([out, in])
//   out[t,o] = (scale_w/scale_x) * sum_i round(x[t,i]*scale_x) * wq[o,i]
// wq in {-1,0,1}, round(x*scale_x) in [-127,127] -> exact int8 GEMM via MFMA i8.

#define M_DIM 8192
#define N_DIM 4096
#define K_DIM 4096
#define W_ELEMS (N_DIM * K_DIM)   // 16777216
#define X_ELEMS (M_DIM * K_DIM)   // 33554432

typedef int   int4v   __attribute__((ext_vector_type(4)));
typedef float float4v __attribute__((ext_vector_type(4)));

// ---- workspace layout ----
// [0]      double sumAbsW (final)
// [8]      uint   maxAbsX bits
// [12]     int    nz count
// [64]     double partials[2048]         (16 KB)
// [32768]  int8   wq [4096*4096]         (16 MB)
// [32768+16MB] int8 xq [8192*4096]       (32 MB)
#define WS_PARTIALS_OFF 64
#define WS_WQ_OFF       32768
#define WS_XQ_OFF       (32768 + W_ELEMS)

__global__ void init_scalars(uint8_t* ws) {
    if (threadIdx.x == 0) {
        *(double*)ws = 0.0;
        ((unsigned*)ws)[2] = 0u;   // max bits (nonneg float -> uint monotone)
        ((int*)ws)[3] = 0;         // nz count
    }
}

// ---- pass 1a: per-block partial sums of |W| (deterministic two-stage) ----
__global__ __launch_bounds__(256) void reduce_absw(const float4v* __restrict__ w, uint8_t* ws) {
    int idx = blockIdx.x * 256 + threadIdx.x;
    int stride = gridDim.x * 256;
    double s = 0.0;
    for (int i = idx; i < W_ELEMS / 4; i += stride) {
        float4v v = w[i];
        s += (double)fabsf(v.x) + (double)fabsf(v.y) + (double)fabsf(v.z) + (double)fabsf(v.w);
    }
    for (int off = 32; off > 0; off >>= 1) s += __shfl_down(s, off);
    __shared__ double ls[4];
    if ((threadIdx.x & 63) == 0) ls[threadIdx.x >> 6] = s;
    __syncthreads();
    if (threadIdx.x == 0) {
        double* partials = (double*)(ws + WS_PARTIALS_OFF);
        partials[blockIdx.x] = ls[0] + ls[1] + ls[2] + ls[3];
    }
}

__global__ __launch_bounds__(256) void final_reduce_w(uint8_t* ws) {
    const double* p = (const double*)(ws + WS_PARTIALS_OFF);
    double s = 0.0;
    for (int i = threadIdx.x; i < 2048; i += 256) s += p[i];
    for (int off = 32; off > 0; off >>= 1) s += __shfl_down(s, off);
    __shared__ double ls[4];
    if ((threadIdx.x & 63) == 0) ls[threadIdx.x >> 6] = s;
    __syncthreads();
    if (threadIdx.x == 0) *(double*)ws = ls[0] + ls[1] + ls[2] + ls[3];
}

// ---- pass 1b: max |x| (exact, order-independent) ----
__global__ __launch_bounds__(256) void reduce_maxx(const float4v* __restrict__ x, uint8_t* ws) {
    int idx = blockIdx.x * 256 + threadIdx.x;
    int stride = gridDim.x * 256;
    float m = 0.0f;
    for (int i = idx; i < X_ELEMS / 4; i += stride) {
        float4v v = x[i];
        m = fmaxf(m, fmaxf(fmaxf(fabsf(v.x), fabsf(v.y)), fmaxf(fabsf(v.z), fabsf(v.w))));
    }
    for (int off = 32; off > 0; off >>= 1) m = fmaxf(m, __shfl_down(m, off));
    __shared__ float ls[4];
    if ((threadIdx.x & 63) == 0) ls[threadIdx.x >> 6] = m;
    __syncthreads();
    if (threadIdx.x == 0) {
        float bm = fmaxf(fmaxf(ls[0], ls[1]), fmaxf(ls[2], ls[3]));
        atomicMax((unsigned*)(ws + 8), __float_as_uint(bm));  // native uint atomic
    }
}

// ---- pass 2a: ternary-quantize W -> int8, count nonzeros ----
__global__ __launch_bounds__(256) void quant_w(const float4v* __restrict__ w, int8_t* __restrict__ wq,
                                               uint8_t* ws) {
    const double sumAbs = *(const double*)ws;
    const float thr = 0.7f * (float)(sumAbs * (1.0 / 16777216.0));  // 0.7f * abs_mean
    int t = blockIdx.x * 256 + threadIdx.x;   // one thread per 16 elements
    int4v r;
    int8_t* rc = (int8_t*)&r;
    int nz = 0;
#pragma unroll
    for (int j = 0; j < 4; ++j) {
        float4v v = w[(size_t)t * 4 + j];
#pragma unroll
        for (int c = 0; c < 4; ++c) {
            float f = v[c];
            int8_t q = (fabsf(f) < thr) ? (int8_t)0 : (f > 0.0f ? (int8_t)1 : (int8_t)-1);
            rc[j * 4 + c] = q;
            nz += (q != 0);
        }
    }
    ((int4v*)wq)[t] = r;
    for (int off = 32; off > 0; off >>= 1) nz += __shfl_down(nz, off);
    if ((threadIdx.x & 63) == 0) atomicAdd((int*)(ws + 12), nz);  // native int atomic
}

// ---- pass 2b: int8-quantize x (round half to even, matches jnp.round) ----
__global__ __launch_bounds__(256) void quant_x(const float4v* __restrict__ x, int8_t* __restrict__ xq,
                                               const uint8_t* ws) {
    const float maxAbs = __uint_as_float(((const unsigned*)ws)[2]);
    const float scale_x = 127.0f / fmaxf(maxAbs, 1e-12f);
    int t = blockIdx.x * 256 + threadIdx.x;   // one thread per 16 elements
    int4v r;
    int8_t* rc = (int8_t*)&r;
#pragma unroll
    for (int j = 0; j < 4; ++j) {
        float4v v = x[(size_t)t * 4 + j];
#pragma unroll
        for (int c = 0; c < 4; ++c) {
            rc[j * 4 + c] = (int8_t)(int)rintf(v[c] * scale_x);
        }
    }
    ((int4v*)xq)[t] = r;
}

// ---- pass 3: int8 GEMM, m97 structure ----
// 128x128 tile, BK=128 int8 (A,B tiles 16KB each, single-buffered 2-barrier loop).
// global_load_lds width=16, linear LDS dest + inverse-swizzled global source;
// ds_read_b128 with XOR slot swizzle (slot ^= row&7) -> conflict-free.
__device__ __forceinline__ void load16_to_lds(const void* gsrc, void* ldst) {
    __builtin_amdgcn_global_load_lds(
        (const __attribute__((address_space(1))) uint32_t*)gsrc,
        (__attribute__((address_space(3))) uint32_t*)ldst, 16, 0, 0);
}

__global__ __launch_bounds__(256) void gemm_i8(const int8_t* __restrict__ Aq,  // xq [8192][4096]
                                               const int8_t* __restrict__ Bq,  // wq [4096][4096]
                                               float* __restrict__ out,
                                               const uint8_t* __restrict__ ws) {
    __shared__ int8_t lds[32768];
    int8_t* ldsA = lds;
    int8_t* ldsB = lds + 16384;

    // XCD-aware bijective swizzle (grid = 2048, 2048 % 8 == 0)
    int bid = blockIdx.x;
    int cpx = gridDim.x >> 3;
    int swz = (bid & 7) * cpx + (bid >> 3);
    int bm = swz / (N_DIM / 128);
    int bn = swz % (N_DIM / 128);

    const int tid = threadIdx.x;
    const int lane = tid & 63;
    const int w = tid >> 6;
    const int wr = w >> 1, wc = w & 1;   // 2x2 wave grid, each wave 64x64 out

    const int8_t* Abase = Aq + (size_t)bm * 128 * K_DIM;
    const int8_t* Bbase = Bq + (size_t)bn * 128 * K_DIM;

    int4v acc[4][4] = {};

    for (int kt = 0; kt < K_DIM; kt += 128) {
        __syncthreads();   // previous compute done before overwrite
#pragma unroll
        for (int i = 0; i < 4; ++i) {
            int p = i * 4096 + tid * 16;   // linear byte offset in 16KB tile
            int r = p >> 7;                // row 0..127
            int s = (p >> 4) & 7;          // 16B slot 0..7
            int q = s ^ (r & 7);           // inverse swizzle on the SOURCE
            load16_to_lds(Abase + (size_t)r * K_DIM + kt + q * 16, ldsA + p);
            load16_to_lds(Bbase + (size_t)r * K_DIM + kt + q * 16, ldsB + p);
        }
        __syncthreads();   // staging complete (compiler drains vmcnt before barrier)

#pragma unroll
        for (int kh = 0; kh < 2; ++kh) {
            int4v af[4], bf[4];
            const int qq = kh * 4 + (lane >> 4);   // 16B k-slot within BK=128
#pragma unroll
            for (int m = 0; m < 4; ++m) {
                int rowA = wr * 64 + m * 16 + (lane & 15);
                af[m] = *(const int4v*)(ldsA + rowA * 128 + ((qq ^ (rowA & 7)) << 4));
            }
#pragma unroll
            for (int n = 0; n < 4; ++n) {
                int rowB = wc * 64 + n * 16 + (lane & 15);
                bf[n] = *(const int4v*)(ldsB + rowB * 128 + ((qq ^ (rowB & 7)) << 4));
            }
#pragma unroll
            for (int m = 0; m < 4; ++m)
#pragma unroll
                for (int n = 0; n < 4; ++n)
                    acc[m][n] = __builtin_amdgcn_mfma_i32_16x16x64_i8(af[m], bf[n], acc[m][n], 0, 0, 0);
        }
    }

    // epilogue: combined scale from ws scalars
    const double sumAbs = *(const double*)ws;
    const float abs_mean = (float)(sumAbs * (1.0 / 16777216.0));
    const float nzm = (float)(((const int*)ws)[3]) * (1.0f / 16777216.0f) + 1e-8f;
    const float scale_w = abs_mean / nzm;
    const float maxAbs = __uint_as_float(((const unsigned*)ws)[2]);
    const float scale_x = 127.0f / fmaxf(maxAbs, 1e-12f);
    const float cs = scale_w / scale_x;

    // C/D layout: col = lane&15, row = (lane>>4)*4 + reg  (dtype-independent on gfx950)
    const int orow0 = bm * 128 + wr * 64 + (lane >> 4) * 4;
    const int ocol0 = bn * 128 + wc * 64 + (lane & 15);
#pragma unroll
    for (int m = 0; m < 4; ++m)
#pragma unroll
        for (int n = 0; n < 4; ++n)
#pragma unroll
            for (int j = 0; j < 4; ++j) {
                int row = orow0 + m * 16 + j;
                int col = ocol0 + n * 16;
                out[(size_t)row * N_DIM + col] = (float)acc[m][n][j] * cs;
            }
}

extern "C" void kernel_launch(void* const* d_in, const int* in_sizes, int n_in,
                              void* d_out, int out_size, void* d_ws, size_t ws_size,
                              hipStream_t stream) {
    const float* x = (const float*)d_in[0];     // [8192, 4096]
    const float* wgt = (const float*)d_in[1];   // [4096, 4096]
    float* out = (float*)d_out;
    uint8_t* ws = (uint8_t*)d_ws;
    int8_t* wq = (int8_t*)(ws + WS_WQ_OFF);
    int8_t* xq = (int8_t*)(ws + WS_XQ_OFF);

    init_scalars<<<1, 64, 0, stream>>>(ws);
    reduce_absw<<<2048, 256, 0, stream>>>((const float4v*)wgt, ws);
    final_reduce_w<<<1, 256, 0, stream>>>(ws);
    reduce_maxx<<<2048, 256, 0, stream>>>((const float4v*)x, ws);
    quant_w<<<4096, 256, 0, stream>>>((const float4v*)wgt, wq, ws);
    quant_x<<<8192, 256, 0, stream>>>((const float4v*)x, xq, ws);
    gemm_i8<<<2048, 256, 0, stream>>>(xq, wq, out, ws);
}

// Round 2
// 488.317 us; speedup vs baseline: 1.3884x; 1.3884x over previous
//
#include <hip/hip_runtime.h>
#include <stdint.h>

// BitLinear forward: x[8192,4096] fp32, weight[4096,4096] fp32 ([out,in])
//   out[t,o] = cs * sum_i round(x[t,i]*scale_x) * wq[o,i],  cs = scale_w/scale_x
// wq in {-1,0,1}, round(x*scale_x) in [-127,127] -> exact int8 MFMA GEMM.

#define M_DIM 8192
#define N_DIM 4096
#define K_DIM 4096
#define W_ELEMS (N_DIM * K_DIM)   // 16777216
#define X_ELEMS (M_DIM * K_DIM)   // 33554432

typedef int   int4v   __attribute__((ext_vector_type(4)));
typedef float float4v __attribute__((ext_vector_type(4)));

// ---- workspace layout ----
#define WS_ABSMEAN 0       // float
#define WS_SCALEX  4       // float
#define WS_THR     8       // float
#define WS_CS      16      // float (final combined scale)
#define WS_WSUM    64      // 1024 doubles (8 KB)
#define WS_XMAX    16384   // 2048 floats  (8 KB)
#define WS_NZ      24576   // 1024 ints    (4 KB)
#define WS_WQ_OFF  32768   // int8 wq, 16 MB
#define WS_XQ_OFF  (32768 + W_ELEMS)  // int8 xq, 32 MB

// ---- pass 1: fused partial reductions (sum|W| + max|x|), no atomics ----
__global__ __launch_bounds__(256) void pass1(const float4v* __restrict__ w,
                                             const float4v* __restrict__ x,
                                             uint8_t* ws) {
    const int tid = threadIdx.x;
    __shared__ double lsd[4];
    __shared__ float lsf[4];
    if (blockIdx.x < 1024) {
        // sum |W|: 1024 blocks x 256 threads x 16 float4 = 16.7M elems
        int idx = blockIdx.x * 256 + tid;
        double s = 0.0;
#pragma unroll 4
        for (int it = 0; it < 16; ++it) {
            float4v v = w[idx + it * 262144];
            s += (double)fabsf(v.x) + (double)fabsf(v.y) + (double)fabsf(v.z) + (double)fabsf(v.w);
        }
        for (int off = 32; off > 0; off >>= 1) s += __shfl_down(s, off);
        if ((tid & 63) == 0) lsd[tid >> 6] = s;
        __syncthreads();
        if (tid == 0) ((double*)(ws + WS_WSUM))[blockIdx.x] = lsd[0] + lsd[1] + lsd[2] + lsd[3];
    } else {
        // max |x|: 2048 blocks x 256 threads x 16 float4 = 33.5M elems
        int b = blockIdx.x - 1024;
        int idx = b * 256 + tid;
        float m = 0.0f;
#pragma unroll 4
        for (int it = 0; it < 16; ++it) {
            float4v v = x[idx + it * 524288];
            m = fmaxf(m, fmaxf(fmaxf(fabsf(v.x), fabsf(v.y)), fmaxf(fabsf(v.z), fabsf(v.w))));
        }
        for (int off = 32; off > 0; off >>= 1) m = fmaxf(m, __shfl_down(m, off));
        if ((tid & 63) == 0) lsf[tid >> 6] = m;
        __syncthreads();
        if (tid == 0) ((float*)(ws + WS_XMAX))[b] = fmaxf(fmaxf(lsf[0], lsf[1]), fmaxf(lsf[2], lsf[3]));
    }
}

// ---- pass 2: finalize scalars ----
__global__ __launch_bounds__(256) void pass2(uint8_t* ws) {
    const int tid = threadIdx.x;
    const double* wp = (const double*)(ws + WS_WSUM);
    const float* xp = (const float*)(ws + WS_XMAX);
    double s = wp[tid] + wp[tid + 256] + wp[tid + 512] + wp[tid + 768];
    float m = 0.0f;
#pragma unroll
    for (int j = 0; j < 8; ++j) m = fmaxf(m, xp[tid + j * 256]);
    for (int off = 32; off > 0; off >>= 1) {
        s += __shfl_down(s, off);
        m = fmaxf(m, __shfl_down(m, off));
    }
    __shared__ double lsd[4];
    __shared__ float lsf[4];
    if ((tid & 63) == 0) { lsd[tid >> 6] = s; lsf[tid >> 6] = m; }
    __syncthreads();
    if (tid == 0) {
        double tot = lsd[0] + lsd[1] + lsd[2] + lsd[3];
        float maxAbs = fmaxf(fmaxf(lsf[0], lsf[1]), fmaxf(lsf[2], lsf[3]));
        float abs_mean = (float)(tot * (1.0 / 16777216.0));
        *(float*)(ws + WS_ABSMEAN) = abs_mean;
        *(float*)(ws + WS_SCALEX) = 127.0f / fmaxf(maxAbs, 1e-12f);
        *(float*)(ws + WS_THR) = 0.7f * abs_mean;
    }
}

// ---- pass 3: fused quantization W->ternary int8 (+nz partials), x->int8 ----
__global__ __launch_bounds__(256) void quant(const float4v* __restrict__ w,
                                             const float4v* __restrict__ x,
                                             uint8_t* ws) {
    const int tid = threadIdx.x;
    uint32_t* wq = (uint32_t*)(ws + WS_WQ_OFF);
    uint32_t* xq = (uint32_t*)(ws + WS_XQ_OFF);
    if (blockIdx.x < 1024) {
        const float thr = *(const float*)(ws + WS_THR);
        int idx = blockIdx.x * 256 + tid;
        int nz = 0;
        for (int it = 0; it < 16; ++it) {
            int i = idx + it * 262144;
            float4v v = w[i];
            uint32_t pk = 0;
#pragma unroll
            for (int c = 0; c < 4; ++c) {
                float f = v[c];
                int q = (fabsf(f) < thr) ? 0 : (f > 0.0f ? 1 : -1);
                nz += (q != 0);
                pk |= (uint32_t)(q & 0xff) << (8 * c);
            }
            wq[i] = pk;
        }
        for (int off = 32; off > 0; off >>= 1) nz += __shfl_down(nz, off);
        __shared__ int lsn[4];
        if ((tid & 63) == 0) lsn[tid >> 6] = nz;
        __syncthreads();
        if (tid == 0) ((int*)(ws + WS_NZ))[blockIdx.x] = lsn[0] + lsn[1] + lsn[2] + lsn[3];
    } else {
        const float sx = *(const float*)(ws + WS_SCALEX);
        int b = blockIdx.x - 1024;
        int idx = b * 256 + tid;
        for (int it = 0; it < 16; ++it) {
            int i = idx + it * 524288;
            float4v v = x[i];
            uint32_t pk = 0;
#pragma unroll
            for (int c = 0; c < 4; ++c) {
                int q = (int)rintf(v[c] * sx);   // round half-to-even = jnp.round
                pk |= (uint32_t)(q & 0xff) << (8 * c);
            }
            xq[i] = pk;
        }
    }
}

// ---- pass 4: finalize nz -> combined output scale cs ----
__global__ __launch_bounds__(256) void pass3(uint8_t* ws) {
    const int tid = threadIdx.x;
    const int* np = (const int*)(ws + WS_NZ);
    int s = np[tid] + np[tid + 256] + np[tid + 512] + np[tid + 768];
    for (int off = 32; off > 0; off >>= 1) s += __shfl_down(s, off);
    __shared__ int ls[4];
    if ((tid & 63) == 0) ls[tid >> 6] = s;
    __syncthreads();
    if (tid == 0) {
        float nzm = (float)(ls[0] + ls[1] + ls[2] + ls[3]) * (1.0f / 16777216.0f) + 1e-8f;
        float abs_mean = *(const float*)(ws + WS_ABSMEAN);
        float sx = *(const float*)(ws + WS_SCALEX);
        *(float*)(ws + WS_CS) = (abs_mean / nzm) / sx;  // scale_w / scale_x
    }
}

// ---- pass 5: int8 GEMM, m97 structure (proven round 1; epilogue reads cs) ----
__device__ __forceinline__ void load16_to_lds(const void* gsrc, void* ldst) {
    __builtin_amdgcn_global_load_lds(
        (const __attribute__((address_space(1))) uint32_t*)gsrc,
        (__attribute__((address_space(3))) uint32_t*)ldst, 16, 0, 0);
}

__global__ __launch_bounds__(256) void gemm_i8(const int8_t* __restrict__ Aq,  // xq [8192][4096]
                                               const int8_t* __restrict__ Bq,  // wq [4096][4096]
                                               float* __restrict__ out,
                                               const uint8_t* __restrict__ ws) {
    __shared__ int8_t lds[32768];
    int8_t* ldsA = lds;
    int8_t* ldsB = lds + 16384;

    // XCD-aware bijective swizzle (grid = 2048, 2048 % 8 == 0)
    int bid = blockIdx.x;
    int cpx = gridDim.x >> 3;
    int swz = (bid & 7) * cpx + (bid >> 3);
    int bm = swz / (N_DIM / 128);
    int bn = swz % (N_DIM / 128);

    const int tid = threadIdx.x;
    const int lane = tid & 63;
    const int w = tid >> 6;
    const int wr = w >> 1, wc = w & 1;   // 2x2 wave grid, each wave 64x64 out

    const int8_t* Abase = Aq + (size_t)bm * 128 * K_DIM;
    const int8_t* Bbase = Bq + (size_t)bn * 128 * K_DIM;

    int4v acc[4][4] = {};

    for (int kt = 0; kt < K_DIM; kt += 128) {
        __syncthreads();   // previous compute done before overwrite
#pragma unroll
        for (int i = 0; i < 4; ++i) {
            int p = i * 4096 + tid * 16;   // linear byte offset in 16KB tile
            int r = p >> 7;                // row 0..127
            int s = (p >> 4) & 7;          // 16B slot 0..7
            int q = s ^ (r & 7);           // inverse swizzle on the SOURCE
            load16_to_lds(Abase + (size_t)r * K_DIM + kt + q * 16, ldsA + p);
            load16_to_lds(Bbase + (size_t)r * K_DIM + kt + q * 16, ldsB + p);
        }
        __syncthreads();   // staging complete

#pragma unroll
        for (int kh = 0; kh < 2; ++kh) {
            int4v af[4], bf[4];
            const int qq = kh * 4 + (lane >> 4);   // 16B k-slot within BK=128
#pragma unroll
            for (int m = 0; m < 4; ++m) {
                int rowA = wr * 64 + m * 16 + (lane & 15);
                af[m] = *(const int4v*)(ldsA + rowA * 128 + ((qq ^ (rowA & 7)) << 4));
            }
#pragma unroll
            for (int n = 0; n < 4; ++n) {
                int rowB = wc * 64 + n * 16 + (lane & 15);
                bf[n] = *(const int4v*)(ldsB + rowB * 128 + ((qq ^ (rowB & 7)) << 4));
            }
#pragma unroll
            for (int m = 0; m < 4; ++m)
#pragma unroll
                for (int n = 0; n < 4; ++n)
                    acc[m][n] = __builtin_amdgcn_mfma_i32_16x16x64_i8(af[m], bf[n], acc[m][n], 0, 0, 0);
        }
    }

    const float cs = *(const float*)(ws + WS_CS);

    // C/D layout: col = lane&15, row = (lane>>4)*4 + reg
    const int orow0 = bm * 128 + wr * 64 + (lane >> 4) * 4;
    const int ocol0 = bn * 128 + wc * 64 + (lane & 15);
#pragma unroll
    for (int m = 0; m < 4; ++m)
#pragma unroll
        for (int n = 0; n < 4; ++n)
#pragma unroll
            for (int j = 0; j < 4; ++j) {
                int row = orow0 + m * 16 + j;
                int col = ocol0 + n * 16;
                out[(size_t)row * N_DIM + col] = (float)acc[m][n][j] * cs;
            }
}

extern "C" void kernel_launch(void* const* d_in, const int* in_sizes, int n_in,
                              void* d_out, int out_size, void* d_ws, size_t ws_size,
                              hipStream_t stream) {
    const float4v* x = (const float4v*)d_in[0];     // [8192, 4096]
    const float4v* wgt = (const float4v*)d_in[1];   // [4096, 4096]
    float* out = (float*)d_out;
    uint8_t* ws = (uint8_t*)d_ws;
    int8_t* wq = (int8_t*)(ws + WS_WQ_OFF);
    int8_t* xq = (int8_t*)(ws + WS_XQ_OFF);

    pass1<<<3072, 256, 0, stream>>>(wgt, x, ws);
    pass2<<<1, 256, 0, stream>>>(ws);
    quant<<<3072, 256, 0, stream>>>(wgt, x, ws);
    pass3<<<1, 256, 0, stream>>>(ws);
    gemm_i8<<<2048, 256, 0, stream>>>(xq, wq, out, ws);
}

// Round 3
// 473.035 us; speedup vs baseline: 1.4333x; 1.0323x over previous
//
#include <hip/hip_runtime.h>
#include <stdint.h>

// BitLinear forward: x[8192,4096] fp32, weight[4096,4096] fp32 ([out,in])
//   out[t,o] = cs * sum_i round(x[t,i]*scale_x) * wq[o,i],  cs = scale_w/scale_x
// Exact int8 MFMA GEMM (|dot| <= 4096*127 fits i32).

#define M_DIM 8192
#define N_DIM 4096
#define K_DIM 4096

typedef int   int4v   __attribute__((ext_vector_type(4)));
typedef float float4v __attribute__((ext_vector_type(4)));

// ---- workspace layout ----
#define WS_WSUM 64                      // 2048 doubles (16 KB)
#define WS_XMAX 16448                   // 4096 floats  (16 KB)
#define WS_NZ   32832                   // 2048 ints    (8 KB)
#define WS_WQ   65536                   // int8 wq, 16 MB
#define WS_XQ   (65536 + N_DIM * K_DIM) // int8 xq, 32 MB

// ==== kernel 1: partial reductions (sum|W|, max|x|), no atomics ====
__global__ __launch_bounds__(256) void reduce_k(const float4v* __restrict__ w,
                                                const float4v* __restrict__ x,
                                                uint8_t* ws) {
    const int tid = threadIdx.x;
    __shared__ double lsd[4];
    __shared__ float lsf[4];
    if (blockIdx.x < 2048) {
        int idx = blockIdx.x * 256 + tid;
        double s0 = 0.0, s1 = 0.0;
#pragma unroll
        for (int it = 0; it < 8; it += 2) {
            float4v a = w[idx + it * 524288];
            float4v b = w[idx + (it + 1) * 524288];
            s0 += (double)((fabsf(a.x) + fabsf(a.y)) + (fabsf(a.z) + fabsf(a.w)));
            s1 += (double)((fabsf(b.x) + fabsf(b.y)) + (fabsf(b.z) + fabsf(b.w)));
        }
        double s = s0 + s1;
        for (int off = 32; off > 0; off >>= 1) s += __shfl_down(s, off);
        if ((tid & 63) == 0) lsd[tid >> 6] = s;
        __syncthreads();
        if (tid == 0) ((double*)(ws + WS_WSUM))[blockIdx.x] = lsd[0] + lsd[1] + lsd[2] + lsd[3];
    } else {
        int idx = (blockIdx.x - 2048) * 256 + tid;
        float m0 = 0.0f, m1 = 0.0f;
#pragma unroll
        for (int it = 0; it < 8; it += 2) {
            float4v a = x[idx + it * 1048576];
            float4v b = x[idx + (it + 1) * 1048576];
            m0 = fmaxf(m0, fmaxf(fmaxf(fabsf(a.x), fabsf(a.y)), fmaxf(fabsf(a.z), fabsf(a.w))));
            m1 = fmaxf(m1, fmaxf(fmaxf(fabsf(b.x), fabsf(b.y)), fmaxf(fabsf(b.z), fabsf(b.w))));
        }
        float m = fmaxf(m0, m1);
        for (int off = 32; off > 0; off >>= 1) m = fmaxf(m, __shfl_down(m, off));
        if ((tid & 63) == 0) lsf[tid >> 6] = m;
        __syncthreads();
        if (tid == 0)
            ((float*)(ws + WS_XMAX))[blockIdx.x - 2048] = fmaxf(fmaxf(lsf[0], lsf[1]), fmaxf(lsf[2], lsf[3]));
    }
}

// ==== kernel 2: quantize (each block self-reduces the partials it needs) ====
__global__ __launch_bounds__(256) void quant_k(const float4v* __restrict__ w,
                                               const float4v* __restrict__ x,
                                               uint8_t* ws) {
    const int tid = threadIdx.x;
    __shared__ double lsd[4];
    __shared__ float lsf[4];
    __shared__ int lsn[4];
    if (blockIdx.x < 2048) {
        // thr = 0.7 * mean|W| from the 2048 double partials (identical in every block)
        const double* wp = (const double*)(ws + WS_WSUM);
        double s = 0.0;
#pragma unroll
        for (int j = 0; j < 8; ++j) s += wp[tid + j * 256];
        for (int off = 32; off > 0; off >>= 1) s += __shfl_down(s, off);
        if ((tid & 63) == 0) lsd[tid >> 6] = s;
        __syncthreads();
        const float thr = 0.7f * (float)((lsd[0] + lsd[1] + lsd[2] + lsd[3]) * (1.0 / 16777216.0));

        uint32_t* wq = (uint32_t*)(ws + WS_WQ);
        int idx = blockIdx.x * 256 + tid;
        int nz = 0;
#pragma unroll
        for (int it = 0; it < 8; ++it) {
            int i = idx + it * 524288;
            float4v v = w[i];
            uint32_t pk = 0;
#pragma unroll
            for (int c = 0; c < 4; ++c) {
                float f = v[c];
                int q = (fabsf(f) < thr) ? 0 : (f > 0.0f ? 1 : -1);
                nz += (q != 0);
                pk |= (uint32_t)(q & 0xff) << (8 * c);
            }
            wq[i] = pk;
        }
        for (int off = 32; off > 0; off >>= 1) nz += __shfl_down(nz, off);
        if ((tid & 63) == 0) lsn[tid >> 6] = nz;
        __syncthreads();
        if (tid == 0) ((int*)(ws + WS_NZ))[blockIdx.x] = lsn[0] + lsn[1] + lsn[2] + lsn[3];
    } else {
        const float* xp = (const float*)(ws + WS_XMAX);
        float m = 0.0f;
#pragma unroll
        for (int j = 0; j < 16; ++j) m = fmaxf(m, xp[tid + j * 256]);
        for (int off = 32; off > 0; off >>= 1) m = fmaxf(m, __shfl_down(m, off));
        if ((tid & 63) == 0) lsf[tid >> 6] = m;
        __syncthreads();
        const float maxAbs = fmaxf(fmaxf(lsf[0], lsf[1]), fmaxf(lsf[2], lsf[3]));
        const float sx = 127.0f / fmaxf(maxAbs, 1e-12f);

        uint32_t* xq = (uint32_t*)(ws + WS_XQ);
        int idx = (blockIdx.x - 2048) * 256 + tid;
#pragma unroll
        for (int it = 0; it < 8; ++it) {
            int i = idx + it * 1048576;
            float4v v = x[i];
            uint32_t pk = 0;
#pragma unroll
            for (int c = 0; c < 4; ++c) {
                int q = (int)rintf(v[c] * sx);   // round half-to-even = jnp.round
                pk |= (uint32_t)(q & 0xff) << (8 * c);
            }
            xq[i] = pk;
        }
    }
}

// ==== kernel 3: int8 GEMM, 256x256 tile, 4-phase/K-tile, counted vmcnt ====
__device__ __forceinline__ void load16_to_lds(const void* gsrc, void* ldst) {
    __builtin_amdgcn_global_load_lds(
        (const __attribute__((address_space(1))) uint32_t*)gsrc,
        (__attribute__((address_space(3))) uint32_t*)ldst, 16, 0, 0);
}

__global__ __launch_bounds__(512, 2) void gemm_i8(const uint8_t* __restrict__ ws,
                                                  float* __restrict__ out) {
    alignas(16) __shared__ int8_t lds[131072];  // [buf][A 32K | B 32K]
    __shared__ int nzw[8];
    __shared__ float cs_sh;

    const int tid = threadIdx.x;
    const int lane = tid & 63;
    const int w = tid >> 6;
    const int wr = w >> 2, wc = w & 3;   // 2x4 wave grid; per-wave out = 128x64

    const int8_t* Aq = (const int8_t*)(ws + WS_XQ);  // [8192][4096]
    const int8_t* Bq = (const int8_t*)(ws + WS_WQ);  // [4096][4096]

    // --- preamble: cs = (abs_mean / nz_mean) / scale_x from partials ---
    {
        const double* wp = (const double*)(ws + WS_WSUM);
        const float* xp = (const float*)(ws + WS_XMAX);
        const int* np = (const int*)(ws + WS_NZ);
        double s = wp[tid] + wp[tid + 512] + wp[tid + 1024] + wp[tid + 1536];
        float mx = 0.0f;
#pragma unroll
        for (int j = 0; j < 8; ++j) mx = fmaxf(mx, xp[tid + j * 512]);
        int nv = np[tid] + np[tid + 512] + np[tid + 1024] + np[tid + 1536];
        for (int off = 32; off > 0; off >>= 1) {
            s += __shfl_down(s, off);
            mx = fmaxf(mx, __shfl_down(mx, off));
            nv += __shfl_down(nv, off);
        }
        __shared__ double sd[8];
        __shared__ float sf[8];
        if (lane == 0) { sd[w] = s; sf[w] = mx; nzw[w] = nv; }
        __syncthreads();
        if (tid == 0) {
            double st = 0.0; float mt = 0.0f; int nt = 0;
#pragma unroll
            for (int j = 0; j < 8; ++j) { st += sd[j]; mt = fmaxf(mt, sf[j]); nt += nzw[j]; }
            float abs_mean = (float)(st * (1.0 / 16777216.0));
            float nzm = (float)nt * (1.0f / 16777216.0f) + 1e-8f;
            float sx = 127.0f / fmaxf(mt, 1e-12f);
            cs_sh = (abs_mean / nzm) / sx;
        }
        __syncthreads();
    }

    // --- block swizzle: grid 512 (32 bm x 16 bn), 512 % 8 == 0 ---
    int bid = blockIdx.x;
    int cpx = gridDim.x >> 3;
    int swz = (bid & 7) * cpx + (bid >> 3);
    int bm = swz >> 4;
    int bn = swz & 15;

    const int8_t* Abase = Aq + (size_t)bm * 256 * K_DIM;
    const int8_t* Bbase = Bq + (size_t)bn * 256 * K_DIM;

    // stage one K-tile (A 32K + B 32K) into buffer b; 8 global_load_lds/thread.
    // linear LDS dest + inverse-swizzled global source (slot ^= row&7).
    auto stage = [&](int kt, int b) {
        int8_t* dstA = lds + b * 65536;
        int8_t* dstB = lds + b * 65536 + 32768;
#pragma unroll
        for (int i = 0; i < 4; ++i) {
            int p = i * 8192 + tid * 16;          // byte offset in 32KB tile
            int r = p >> 7;                        // row 0..255
            int q = ((p >> 4) & 7) ^ (r & 7);      // source 16B slot
            load16_to_lds(Abase + (size_t)r * K_DIM + kt + q * 16, dstA + p);
            load16_to_lds(Bbase + (size_t)r * K_DIM + kt + q * 16, dstB + p);
        }
    };

    int4v acc[8][4] = {};

    stage(0, 0);
    const int rA0 = wr * 128 + (lane & 15);   // A row base for this lane
    const int rB0 = wc * 64 + (lane & 15);    // B row base
    const int lg = lane >> 4;                 // k-group 0..3
    const int lx = lane & 7;                  // row&7 for all fragment rows

    for (int t = 0; t < 32; ++t) {
        const int cur = t & 1;
        if (t < 31) {
            stage((t + 1) * 128, cur ^ 1);                       // next tile -> dead buffer
            asm volatile("s_waitcnt vmcnt(8)" ::: "memory");     // current tile landed, next stays in flight
        } else {
            asm volatile("s_waitcnt vmcnt(0)" ::: "memory");
        }
        __builtin_amdgcn_s_barrier();

        const int8_t* A = lds + cur * 65536;
        const int8_t* B = lds + cur * 65536 + 32768;

#pragma unroll
        for (int kk = 0; kk < 2; ++kk) {
            int4v bf[4];
            const int slot = ((kk * 4 + lg) ^ lx) << 4;
#pragma unroll
            for (int mh = 0; mh < 2; ++mh) {
                int4v af[4];
                if (mh == 0) {
#pragma unroll
                    for (int n = 0; n < 4; ++n)
                        bf[n] = *(const int4v*)(B + (rB0 + n * 16) * 128 + slot);
                }
#pragma unroll
                for (int mi = 0; mi < 4; ++mi)
                    af[mi] = *(const int4v*)(A + (rA0 + (mh * 4 + mi) * 16) * 128 + slot);

                __builtin_amdgcn_s_barrier();
                asm volatile("s_waitcnt lgkmcnt(0)" ::: "memory");
                __builtin_amdgcn_s_setprio(1);
#pragma unroll
                for (int mi = 0; mi < 4; ++mi)
#pragma unroll
                    for (int n = 0; n < 4; ++n)
                        acc[mh * 4 + mi][n] =
                            __builtin_amdgcn_mfma_i32_16x16x64_i8(af[mi], bf[n], acc[mh * 4 + mi][n], 0, 0, 0);
                __builtin_amdgcn_s_setprio(0);
                __builtin_amdgcn_s_barrier();
            }
        }
    }

    // --- epilogue ---
    const float cs = cs_sh;
    const int orow0 = bm * 256 + wr * 128 + (lane >> 4) * 4;
    const int ocol0 = bn * 256 + wc * 64 + (lane & 15);
#pragma unroll
    for (int m = 0; m < 8; ++m)
#pragma unroll
        for (int n = 0; n < 4; ++n)
#pragma unroll
            for (int j = 0; j < 4; ++j) {
                int row = orow0 + m * 16 + j;
                int col = ocol0 + n * 16;
                out[(size_t)row * N_DIM + col] = (float)acc[m][n][j] * cs;
            }
}

extern "C" void kernel_launch(void* const* d_in, const int* in_sizes, int n_in,
                              void* d_out, int out_size, void* d_ws, size_t ws_size,
                              hipStream_t stream) {
    const float4v* x = (const float4v*)d_in[0];     // [8192, 4096]
    const float4v* wgt = (const float4v*)d_in[1];   // [4096, 4096]
    float* out = (float*)d_out;
    uint8_t* ws = (uint8_t*)d_ws;

    reduce_k<<<6144, 256, 0, stream>>>(wgt, x, ws);
    quant_k<<<6144, 256, 0, stream>>>(wgt, x, ws);
    gemm_i8<<<512, 512, 0, stream>>>(ws, out);
}